// Round 1
// baseline (1028.322 us; speedup 1.0000x reference)
//
#include <hip/hip_runtime.h>
#include <math.h>

#define ZEPS  0.01f
#define ZMEAN 0.1307f
#define ZSIGMA 0.3081f

constexpr int D = 1024, H = 4096, O = 10;

// ---------------------------------------------------------------------------
// ReLU-zonotope per-row parameters.
// Given v and radius r: u=v+r, l=v-r, slope=u/(u-l), term=(1-slope)*u/2.
//   dead (u<=0):        v'=0,   a=0,     t=0
//   crossing (u>0,l<0): v'=slope*v+term, a=slope, t=term
//   live:               v'=v,   a=1,     t=0
// a scales the existing eps row; t is the appended fresh-error column value.
__device__ inline void relu_params(float v, float r, float& vout, float& aout, float& tout) {
    float u = v + r, l = v - r;
    float denom = u - l;
    float slope = u / (denom == 0.f ? 1.f : denom);
    float term = (1.f - slope) * u * 0.5f;
    bool dead = (u <= 0.f);
    bool crossing = (u > 0.f) && (l < 0.f);
    vout = dead ? 0.f : (crossing ? (slope * v + term) : v);
    aout = dead ? 0.f : (crossing ? slope : 1.f);
    tout = (!dead && crossing) ? term : 0.f;
}

// ---------------------------------------------------------------------------
__global__ void k_setup(const float* __restrict__ x, float* __restrict__ values,
                        float* __restrict__ dcol, float* __restrict__ r3) {
    int j = blockIdx.x * blockDim.x + threadIdx.x;
    if (j < D) {
        float v = x[j];
        float up = fminf(v + ZEPS, 1.f);
        float lo = fmaxf(v - ZEPS, 0.f);
        values[j] = (up + lo - ZMEAN) / ZSIGMA;  // faithful: values = u+l, then normalized
        dcol[j]   = up / ZSIGMA;                 // eps diag = values-lower = upper, /sigma
    }
    if (blockIdx.x == 0 && threadIdx.x < 16) r3[threadIdx.x] = 0.f;  // zero atomic target (ws is poisoned)
}

// Layer 1 + ReLU-1 fused: v1 = W1@values+b1 ; r1 = |W1| @ d  (eps1 is diagonal-scaled W1)
__global__ __launch_bounds__(256) void k_layer1(const float* __restrict__ W1, const float* __restrict__ b1,
                                                const float* __restrict__ values, const float* __restrict__ dcol,
                                                float* __restrict__ v1p, float* __restrict__ a1,
                                                float* __restrict__ t1) {
    int i = blockIdx.x, tid = threadIdx.x;
    const float* row = W1 + (size_t)i * D;
    float sv = 0.f, sr = 0.f;
    for (int j = tid; j < D; j += 256) {
        float w = row[j];
        sv += w * values[j];
        sr += fabsf(w) * dcol[j];
    }
    __shared__ float red1[256], red2[256];
    red1[tid] = sv; red2[tid] = sr;
    __syncthreads();
    for (int off = 128; off; off >>= 1) {
        if (tid < off) { red1[tid] += red1[tid + off]; red2[tid] += red2[tid + off]; }
        __syncthreads();
    }
    if (tid == 0) {
        float v = red1[0] + b1[i];
        relu_params(v, red2[0], v1p[i], a1[i], t1[i]);
    }
}

// W1s[k][j] = a1[k] * W1[k][j] * d[j]   (so eps2 = W2 @ W1s, no epilogue scaling)
__global__ void k_scale(const float* __restrict__ W1, const float* __restrict__ a1,
                        const float* __restrict__ dcol, float* __restrict__ W1s) {
    int idx = blockIdx.x * blockDim.x + threadIdx.x;  // float4 index over H*D/4
    int j4 = idx % (D / 4), k = idx / (D / 4);
    float4 w = ((const float4*)W1)[idx];
    float a = a1[k];
    float4 dd = ((const float4*)dcol)[j4];
    float4 o;
    o.x = a * w.x * dd.x; o.y = a * w.y * dd.y; o.z = a * w.z * dd.z; o.w = a * w.w * dd.w;
    ((float4*)W1s)[idx] = o;
}

// eps2 = W2 @ W1s : M=4096, K=4096, N=1024, fp32 vector GEMM.
// 128x128 block tile, BK=16, 16x16 threads x (8x8 microtile).
#define BM 128
#define BN 128
#define BK 16
__global__ __launch_bounds__(256) void k_gemm(const float* __restrict__ A, const float* __restrict__ B,
                                              float* __restrict__ C) {
    const int M = H, N = D, K = H;
    __shared__ float As[BK][BM];  // transposed A tile
    __shared__ float Bs[BK][BN];
    int bm = blockIdx.y * BM, bn = blockIdx.x * BN;
    int tid = threadIdx.x;
    int tx = tid % 16, ty = tid / 16;
    float acc[8][8];
#pragma unroll
    for (int p = 0; p < 8; ++p)
#pragma unroll
        for (int q = 0; q < 8; ++q) acc[p][q] = 0.f;

    for (int k0 = 0; k0 < K; k0 += BK) {
#pragma unroll
        for (int t = tid; t < BM * BK / 4; t += 256) {
            int row = t >> 2, c4 = t & 3;
            float4 a = *(const float4*)&A[(size_t)(bm + row) * K + k0 + c4 * 4];
            As[c4 * 4 + 0][row] = a.x; As[c4 * 4 + 1][row] = a.y;
            As[c4 * 4 + 2][row] = a.z; As[c4 * 4 + 3][row] = a.w;
        }
#pragma unroll
        for (int t = tid; t < BK * BN / 4; t += 256) {
            int row = t >> 5, c4 = t & 31;
            *(float4*)&Bs[row][c4 * 4] = *(const float4*)&B[(size_t)(k0 + row) * N + bn + c4 * 4];
        }
        __syncthreads();
#pragma unroll
        for (int kk = 0; kk < BK; ++kk) {
            float4 a0 = *(const float4*)&As[kk][ty * 8];
            float4 a1v = *(const float4*)&As[kk][ty * 8 + 4];
            float4 b0 = *(const float4*)&Bs[kk][tx * 8];
            float4 b1v = *(const float4*)&Bs[kk][tx * 8 + 4];
            float ar[8] = {a0.x, a0.y, a0.z, a0.w, a1v.x, a1v.y, a1v.z, a1v.w};
            float br[8] = {b0.x, b0.y, b0.z, b0.w, b1v.x, b1v.y, b1v.z, b1v.w};
#pragma unroll
            for (int p = 0; p < 8; ++p)
#pragma unroll
                for (int q = 0; q < 8; ++q) acc[p][q] += ar[p] * br[q];
        }
        __syncthreads();
    }
#pragma unroll
    for (int p = 0; p < 8; ++p) {
        size_t row = bm + ty * 8 + p;
#pragma unroll
        for (int q = 0; q < 8; q += 4) {
            *(float4*)&C[row * N + bn + tx * 8 + q] =
                make_float4(acc[p][q], acc[p][q + 1], acc[p][q + 2], acc[p][q + 3]);
        }
    }
}

// v2 = W2@v1p + b2 ; t2col = W2@t1  (the appended-column from ReLU-1)
__global__ __launch_bounds__(256) void k_v2(const float* __restrict__ W2, const float* __restrict__ b2,
                                            const float* __restrict__ v1p, const float* __restrict__ t1,
                                            float* __restrict__ v2, float* __restrict__ t2col) {
    int i = blockIdx.x, tid = threadIdx.x;
    const float* row = W2 + (size_t)i * H;
    float sv = 0.f, st = 0.f;
    for (int k = tid; k < H; k += 256) {
        float w = row[k];
        sv += w * v1p[k];
        st += w * t1[k];
    }
    __shared__ float red1[256], red2[256];
    red1[tid] = sv; red2[tid] = st;
    __syncthreads();
    for (int off = 128; off; off >>= 1) {
        if (tid < off) { red1[tid] += red1[tid + off]; red2[tid] += red2[tid + off]; }
        __syncthreads();
    }
    if (tid == 0) { v2[i] = red1[0] + b2[i]; t2col[i] = red2[0]; }
}

// r2 = rowsum|eps2| + |t2col| ; ReLU-2 params
__global__ __launch_bounds__(256) void k_relu2(const float* __restrict__ eps2, const float* __restrict__ t2col,
                                               const float* __restrict__ v2, float* __restrict__ v2p,
                                               float* __restrict__ a2, float* __restrict__ t2) {
    int i = blockIdx.x, tid = threadIdx.x;
    const float* row = eps2 + (size_t)i * D;
    float s = 0.f;
    for (int j = tid; j < D; j += 256) s += fabsf(row[j]);
    __shared__ float red[256];
    red[tid] = s;
    __syncthreads();
    for (int off = 128; off; off >>= 1) {
        if (tid < off) red[tid] += red[tid + off];
        __syncthreads();
    }
    if (tid == 0) {
        float r = red[0] + fabsf(t2col[i]);
        relu_params(v2[i], r, v2p[i], a2[i], t2[i]);
    }
}

// r3[o] += sum_j |sum_i W3[o,i]*a2[i]*eps2[i,j]|  for the 1024 original columns.
// Block = 64 columns x 4 i-slices (abs only after full-i partials are combined).
__global__ __launch_bounds__(256) void k_eps3(const float* __restrict__ eps2, const float* __restrict__ W3,
                                              const float* __restrict__ a2, float* __restrict__ r3) {
    int c = threadIdx.x & 63, s = threadIdx.x >> 6;
    int j = blockIdx.x * 64 + c;
    float acc[O];
#pragma unroll
    for (int o = 0; o < O; ++o) acc[o] = 0.f;
    int i0 = s * (H / 4), i1 = i0 + (H / 4);
    for (int i = i0; i < i1; ++i) {
        float ea = eps2[(size_t)i * D + j] * a2[i];
#pragma unroll
        for (int o = 0; o < O; ++o) acc[o] += W3[(size_t)o * H + i] * ea;
    }
    __shared__ float sm[4][64][O + 1];
#pragma unroll
    for (int o = 0; o < O; ++o) sm[s][c][o] = acc[o];
    __syncthreads();
    __shared__ float red[64];
    for (int o = 0; o < O; ++o) {
        if (threadIdx.x < 64) {
            float t = sm[0][threadIdx.x][o] + sm[1][threadIdx.x][o] +
                      sm[2][threadIdx.x][o] + sm[3][threadIdx.x][o];
            red[threadIdx.x] = fabsf(t);
        }
        __syncthreads();
        for (int off = 32; off; off >>= 1) {
            if (threadIdx.x < off) red[threadIdx.x] += red[threadIdx.x + off];
            __syncthreads();
        }
        if (threadIdx.x == 0) atomicAdd(&r3[o], red[0]);
        __syncthreads();
    }
}

// v3 = W3@v2p + b3 ; c1 = W3@(a2*t2col) ; c2 = W3@t2 ; u/l = v3 +- (r3+|c1|+|c2|)
__global__ __launch_bounds__(256) void k_final(const float* __restrict__ W3, const float* __restrict__ b3,
                                               const float* __restrict__ v2p, const float* __restrict__ a2,
                                               const float* __restrict__ t2col, const float* __restrict__ t2,
                                               const float* __restrict__ r3, float* __restrict__ out) {
    int o = blockIdx.x, tid = threadIdx.x;
    const float* row = W3 + (size_t)o * H;
    float sv = 0.f, s1 = 0.f, s2 = 0.f;
    for (int i = tid; i < H; i += 256) {
        float w = row[i];
        sv += w * v2p[i];
        s1 += w * a2[i] * t2col[i];
        s2 += w * t2[i];
    }
    __shared__ float ra[256], rb[256], rc[256];
    ra[tid] = sv; rb[tid] = s1; rc[tid] = s2;
    __syncthreads();
    for (int off = 128; off; off >>= 1) {
        if (tid < off) { ra[tid] += ra[tid + off]; rb[tid] += rb[tid + off]; rc[tid] += rc[tid + off]; }
        __syncthreads();
    }
    if (tid == 0) {
        float v3 = ra[0] + b3[o];
        float rr = r3[o] + fabsf(rb[0]) + fabsf(rc[0]);
        out[o] = v3 + rr;       // u
        out[O + o] = v3 - rr;   // l
    }
}

// ---------------------------------------------------------------------------
extern "C" void kernel_launch(void* const* d_in, const int* in_sizes, int n_in,
                              void* d_out, int out_size, void* d_ws, size_t ws_size,
                              hipStream_t stream) {
    const float* x  = (const float*)d_in[0];
    const float* W1 = (const float*)d_in[1];
    const float* b1 = (const float*)d_in[2];
    const float* W2 = (const float*)d_in[3];
    const float* b2 = (const float*)d_in[4];
    const float* W3 = (const float*)d_in[5];
    const float* b3 = (const float*)d_in[6];
    float* out = (float*)d_out;

    float* p = (float*)d_ws;
    float* values = p; p += D;
    float* dcol   = p; p += D;
    float* v1p    = p; p += H;
    float* a1     = p; p += H;
    float* t1     = p; p += H;
    float* v2     = p; p += H;
    float* t2col  = p; p += H;
    float* v2p    = p; p += H;
    float* a2     = p; p += H;
    float* t2     = p; p += H;
    float* r3     = p; p += 16;
    float* W1s    = p; p += (size_t)H * D;
    float* eps2   = p; p += (size_t)H * D;

    k_setup<<<dim3((D + 255) / 256), 256, 0, stream>>>(x, values, dcol, r3);
    k_layer1<<<H, 256, 0, stream>>>(W1, b1, values, dcol, v1p, a1, t1);
    k_scale<<<(H * D / 4) / 256, 256, 0, stream>>>(W1, a1, dcol, W1s);
    k_gemm<<<dim3(D / BN, H / BM), 256, 0, stream>>>(W2, W1s, eps2);
    k_v2<<<H, 256, 0, stream>>>(W2, b2, v1p, t1, v2, t2col);
    k_relu2<<<H, 256, 0, stream>>>(eps2, t2col, v2, v2p, a2, t2);
    k_eps3<<<D / 64, 256, 0, stream>>>(eps2, W3, a2, r3);
    k_final<<<O, 256, 0, stream>>>(W3, b3, v2p, a2, t2col, t2, r3, out);
}

// Round 2
// 480.911 us; speedup vs baseline: 2.1383x; 2.1383x over previous
//
#include <hip/hip_runtime.h>
#include <math.h>

#define ZEPS  0.01f
#define ZMEAN 0.1307f
#define ZSIGMA 0.3081f

constexpr int D = 1024, H = 4096, O = 10;

using short8 = __attribute__((ext_vector_type(8))) short;
using f32x4  = __attribute__((ext_vector_type(4))) float;

__device__ inline unsigned short f2bf(float x) {  // RNE fp32 -> bf16 bits
    unsigned int u = __float_as_uint(x);
    u += 0x7FFFu + ((u >> 16) & 1u);
    return (unsigned short)(u >> 16);
}

// async 16B/lane global->LDS (lds dest = base + lane*16, wave-uniform base)
__device__ inline void gl_lds16(const void* g, void* l) {
    __builtin_amdgcn_global_load_lds(
        (const __attribute__((address_space(1))) unsigned int*)g,
        (__attribute__((address_space(3))) unsigned int*)l, 16, 0, 0);
}

// ---------------------------------------------------------------------------
__device__ inline void relu_params(float v, float r, float& vout, float& aout, float& tout) {
    float u = v + r, l = v - r;
    float denom = u - l;
    float slope = u / (denom == 0.f ? 1.f : denom);
    float term = (1.f - slope) * u * 0.5f;
    bool dead = (u <= 0.f);
    bool crossing = (u > 0.f) && (l < 0.f);
    vout = dead ? 0.f : (crossing ? (slope * v + term) : v);
    aout = dead ? 0.f : (crossing ? slope : 1.f);
    tout = (!dead && crossing) ? term : 0.f;
}

// ---------------------------------------------------------------------------
__global__ void k_setup(const float* __restrict__ x, float* __restrict__ values,
                        float* __restrict__ dcol, float* __restrict__ r3) {
    int j = blockIdx.x * blockDim.x + threadIdx.x;
    if (j < D) {
        float v = x[j];
        float up = fminf(v + ZEPS, 1.f);
        float lo = fmaxf(v - ZEPS, 0.f);
        values[j] = (up + lo - ZMEAN) / ZSIGMA;
        dcol[j]   = up / ZSIGMA;
    }
    if (blockIdx.x == 0 && threadIdx.x < 16) r3[threadIdx.x] = 0.f;
}

// v1 = W1@values+b1 ; r1 = |W1| @ d ; ReLU-1 params
__global__ __launch_bounds__(256) void k_layer1(const float* __restrict__ W1, const float* __restrict__ b1,
                                                const float* __restrict__ values, const float* __restrict__ dcol,
                                                float* __restrict__ v1p, float* __restrict__ a1,
                                                float* __restrict__ t1) {
    int i = blockIdx.x, tid = threadIdx.x;
    const float* row = W1 + (size_t)i * D;
    float sv = 0.f, sr = 0.f;
    for (int j = tid; j < D; j += 256) {
        float w = row[j];
        sv += w * values[j];
        sr += fabsf(w) * dcol[j];
    }
    __shared__ float red1[256], red2[256];
    red1[tid] = sv; red2[tid] = sr;
    __syncthreads();
    for (int off = 128; off; off >>= 1) {
        if (tid < off) { red1[tid] += red1[tid + off]; red2[tid] += red2[tid + off]; }
        __syncthreads();
    }
    if (tid == 0) {
        float v = red1[0] + b1[i];
        relu_params(v, red2[0], v1p[i], a1[i], t1[i]);
    }
}

// W1sT[j][k] = bf16( a1[k] * W1[k][j] * d[j] )  — transposed, k-contiguous
__global__ __launch_bounds__(256) void k_scaleT(const float* __restrict__ W1, const float* __restrict__ a1,
                                                const float* __restrict__ dcol,
                                                unsigned short* __restrict__ W1sT) {
    __shared__ float tile[32][33];
    int j0 = blockIdx.x * 32, k0 = blockIdx.y * 32;
    int r = threadIdx.x >> 3;         // 0..31
    int c = (threadIdx.x & 7) * 4;    // 0,4,..,28
    float4 w = *(const float4*)&W1[(size_t)(k0 + r) * D + j0 + c];
    float a = a1[k0 + r];
    tile[r][c + 0] = a * w.x * dcol[j0 + c + 0];
    tile[r][c + 1] = a * w.y * dcol[j0 + c + 1];
    tile[r][c + 2] = a * w.z * dcol[j0 + c + 2];
    tile[r][c + 3] = a * w.w * dcol[j0 + c + 3];
    __syncthreads();
    ushort4 o;
    o.x = f2bf(tile[c + 0][r]);
    o.y = f2bf(tile[c + 1][r]);
    o.z = f2bf(tile[c + 2][r]);
    o.w = f2bf(tile[c + 3][r]);
    *(ushort4*)&W1sT[(size_t)(j0 + r) * H + k0 + c] = o;
}

// v2 = W2@v1p + b2 ; t2col = W2@t1 ; fused W2 -> bf16 conversion
__global__ __launch_bounds__(256) void k_v2conv(const float* __restrict__ W2, const float* __restrict__ b2,
                                                const float* __restrict__ v1p, const float* __restrict__ t1,
                                                float* __restrict__ v2, float* __restrict__ t2col,
                                                unsigned short* __restrict__ W2b) {
    int i = blockIdx.x, tid = threadIdx.x;
    const float* row = W2 + (size_t)i * H;
    unsigned short* orow = W2b + (size_t)i * H;
    float sv = 0.f, st = 0.f;
    for (int k0 = tid * 4; k0 < H; k0 += 1024) {
        float4 w = *(const float4*)&row[k0];
        sv += w.x * v1p[k0] + w.y * v1p[k0 + 1] + w.z * v1p[k0 + 2] + w.w * v1p[k0 + 3];
        st += w.x * t1[k0] + w.y * t1[k0 + 1] + w.z * t1[k0 + 2] + w.w * t1[k0 + 3];
        ushort4 o;
        o.x = f2bf(w.x); o.y = f2bf(w.y); o.z = f2bf(w.z); o.w = f2bf(w.w);
        *(ushort4*)&orow[k0] = o;
    }
    __shared__ float red1[256], red2[256];
    red1[tid] = sv; red2[tid] = st;
    __syncthreads();
    for (int off = 128; off; off >>= 1) {
        if (tid < off) { red1[tid] += red1[tid + off]; red2[tid] += red2[tid + off]; }
        __syncthreads();
    }
    if (tid == 0) { v2[i] = red1[0] + b2[i]; t2col[i] = red2[0]; }
}

// ---------------------------------------------------------------------------
// eps2 = W2b @ W1sT^T : A=[M=4096][K=4096] bf16, B=[N=1024][K] bf16 (NT GEMM).
// 128x128 tile, BK=32, 4 waves in 2x2, 64x64 per wave, 16x16x32 MFMA.
// LDS chunk-swizzle: slot (row, c) holds global chunk c ^ ((row>>1)&3)
// -> conflict-free ds_read_b128 while keeping global_load_lds lane-contiguous dest.
#define GBM 128
#define GBN 128
#define GBK 32
__global__ __launch_bounds__(256) void k_gemm_mfma(const unsigned short* __restrict__ A,
                                                   const unsigned short* __restrict__ B,
                                                   float* __restrict__ C) {
    const int M = H, N = D, K = H;
    (void)M;
    __shared__ __align__(16) unsigned short As[GBM * GBK];
    __shared__ __align__(16) unsigned short Bs[GBN * GBK];
    int tid = threadIdx.x;
    int wave = tid >> 6, lane = tid & 63;
    int bm = blockIdx.y * GBM, bn = blockIdx.x * GBN;
    int wm = (wave >> 1) * 64, wn = (wave & 1) * 64;

    // staging geometry: each wave stages rows [wave*32, wave*32+32) of As and Bs
    int sr = lane >> 2;                 // row within 16-row group
    int sc = lane & 3;                  // dest chunk 0..3
    int scp = sc ^ ((sr >> 1) & 3);     // permuted source chunk
    int rowA0 = wave * 32;

    int r15 = lane & 15, quad = lane >> 4;
    int ksw = (r15 >> 1) & 3;           // read-side swizzle key

    f32x4 acc[4][4];
#pragma unroll
    for (int p = 0; p < 4; ++p)
#pragma unroll
        for (int q = 0; q < 4; ++q) acc[p][q] = (f32x4){0.f, 0.f, 0.f, 0.f};

    for (int k0 = 0; k0 < K; k0 += GBK) {
#pragma unroll
        for (int g = 0; g < 2; ++g) {
            int ra = rowA0 + g * 16;
            gl_lds16(&A[(size_t)(bm + ra + sr) * K + k0 + scp * 8], &As[ra * GBK]);
            gl_lds16(&B[(size_t)(bn + ra + sr) * K + k0 + scp * 8], &Bs[ra * GBK]);
        }
        __syncthreads();

        short8 af[4], bf[4];
#pragma unroll
        for (int mt = 0; mt < 4; ++mt) {
            int rA = wm + mt * 16 + r15;
            af[mt] = *(const short8*)&As[rA * GBK + (quad ^ ksw) * 8];
        }
#pragma unroll
        for (int nt = 0; nt < 4; ++nt) {
            int rB = wn + nt * 16 + r15;
            bf[nt] = *(const short8*)&Bs[rB * GBK + (quad ^ ksw) * 8];
        }
#pragma unroll
        for (int mt = 0; mt < 4; ++mt)
#pragma unroll
            for (int nt = 0; nt < 4; ++nt)
                acc[mt][nt] = __builtin_amdgcn_mfma_f32_16x16x32_bf16(af[mt], bf[nt], acc[mt][nt], 0, 0, 0);
        __syncthreads();
    }

    // epilogue: C row = quad*4+reg, col = lane&15
#pragma unroll
    for (int mt = 0; mt < 4; ++mt) {
        int gr = bm + wm + mt * 16 + quad * 4;
#pragma unroll
        for (int nt = 0; nt < 4; ++nt) {
            int gc = bn + wn + nt * 16 + r15;
            C[(size_t)(gr + 0) * N + gc] = acc[mt][nt][0];
            C[(size_t)(gr + 1) * N + gc] = acc[mt][nt][1];
            C[(size_t)(gr + 2) * N + gc] = acc[mt][nt][2];
            C[(size_t)(gr + 3) * N + gc] = acc[mt][nt][3];
        }
    }
}

// r2 = rowsum|eps2| + |t2col| ; ReLU-2 params
__global__ __launch_bounds__(256) void k_relu2(const float* __restrict__ eps2, const float* __restrict__ t2col,
                                               const float* __restrict__ v2, float* __restrict__ v2p,
                                               float* __restrict__ a2, float* __restrict__ t2) {
    int i = blockIdx.x, tid = threadIdx.x;
    const float* row = eps2 + (size_t)i * D;
    float s = 0.f;
    for (int j = tid; j < D; j += 256) s += fabsf(row[j]);
    __shared__ float red[256];
    red[tid] = s;
    __syncthreads();
    for (int off = 128; off; off >>= 1) {
        if (tid < off) red[tid] += red[tid + off];
        __syncthreads();
    }
    if (tid == 0) {
        float r = red[0] + fabsf(t2col[i]);
        relu_params(v2[i], r, v2p[i], a2[i], t2[i]);
    }
}

// r3[o] += sum_j |sum_i W3[o,i]*a2[i]*eps2[i,j]|
__global__ __launch_bounds__(256) void k_eps3(const float* __restrict__ eps2, const float* __restrict__ W3,
                                              const float* __restrict__ a2, float* __restrict__ r3) {
    int c = threadIdx.x & 63, s = threadIdx.x >> 6;
    int j = blockIdx.x * 64 + c;
    float acc[O];
#pragma unroll
    for (int o = 0; o < O; ++o) acc[o] = 0.f;
    int i0 = s * (H / 4), i1 = i0 + (H / 4);
    for (int i = i0; i < i1; ++i) {
        float ea = eps2[(size_t)i * D + j] * a2[i];
#pragma unroll
        for (int o = 0; o < O; ++o) acc[o] += W3[(size_t)o * H + i] * ea;
    }
    __shared__ float sm[4][64][O + 1];
#pragma unroll
    for (int o = 0; o < O; ++o) sm[s][c][o] = acc[o];
    __syncthreads();
    __shared__ float red[64];
    for (int o = 0; o < O; ++o) {
        if (threadIdx.x < 64) {
            float t = sm[0][threadIdx.x][o] + sm[1][threadIdx.x][o] +
                      sm[2][threadIdx.x][o] + sm[3][threadIdx.x][o];
            red[threadIdx.x] = fabsf(t);
        }
        __syncthreads();
        for (int off = 32; off; off >>= 1) {
            if (threadIdx.x < off) red[threadIdx.x] += red[threadIdx.x + off];
            __syncthreads();
        }
        if (threadIdx.x == 0) atomicAdd(&r3[o], red[0]);
        __syncthreads();
    }
}

// v3 = W3@v2p + b3 ; c1 = W3@(a2*t2col) ; c2 = W3@t2 ; out = v3 +- (r3+|c1|+|c2|)
__global__ __launch_bounds__(256) void k_final(const float* __restrict__ W3, const float* __restrict__ b3,
                                               const float* __restrict__ v2p, const float* __restrict__ a2,
                                               const float* __restrict__ t2col, const float* __restrict__ t2,
                                               const float* __restrict__ r3, float* __restrict__ out) {
    int o = blockIdx.x, tid = threadIdx.x;
    const float* row = W3 + (size_t)o * H;
    float sv = 0.f, s1 = 0.f, s2 = 0.f;
    for (int i = tid; i < H; i += 256) {
        float w = row[i];
        sv += w * v2p[i];
        s1 += w * a2[i] * t2col[i];
        s2 += w * t2[i];
    }
    __shared__ float ra[256], rb[256], rc[256];
    ra[tid] = sv; rb[tid] = s1; rc[tid] = s2;
    __syncthreads();
    for (int off = 128; off; off >>= 1) {
        if (tid < off) { ra[tid] += ra[tid + off]; rb[tid] += rb[tid + off]; rc[tid] += rc[tid + off]; }
        __syncthreads();
    }
    if (tid == 0) {
        float v3 = ra[0] + b3[o];
        float rr = r3[o] + fabsf(rb[0]) + fabsf(rc[0]);
        out[o] = v3 + rr;       // u
        out[O + o] = v3 - rr;   // l
    }
}

// ---------------------------------------------------------------------------
extern "C" void kernel_launch(void* const* d_in, const int* in_sizes, int n_in,
                              void* d_out, int out_size, void* d_ws, size_t ws_size,
                              hipStream_t stream) {
    const float* x  = (const float*)d_in[0];
    const float* W1 = (const float*)d_in[1];
    const float* b1 = (const float*)d_in[2];
    const float* W2 = (const float*)d_in[3];
    const float* b2 = (const float*)d_in[4];
    const float* W3 = (const float*)d_in[5];
    const float* b3 = (const float*)d_in[6];
    float* out = (float*)d_out;

    float* p = (float*)d_ws;
    float* values = p; p += D;
    float* dcol   = p; p += D;
    float* v1p    = p; p += H;
    float* a1     = p; p += H;
    float* t1     = p; p += H;
    float* v2     = p; p += H;
    float* t2col  = p; p += H;
    float* v2p    = p; p += H;
    float* a2     = p; p += H;
    float* t2     = p; p += H;
    float* r3     = p; p += 16;
    p += 16;  // pad to keep 16B alignment for what follows
    float* eps2   = p; p += (size_t)H * D;                    // 16 MB fp32
    unsigned short* W2b  = (unsigned short*)p;                // 32 MB bf16
    unsigned short* W1sT = W2b + (size_t)H * H;               // 8 MB bf16

    k_setup<<<dim3((D + 255) / 256), 256, 0, stream>>>(x, values, dcol, r3);
    k_layer1<<<H, 256, 0, stream>>>(W1, b1, values, dcol, v1p, a1, t1);
    k_scaleT<<<dim3(D / 32, H / 32), 256, 0, stream>>>(W1, a1, dcol, W1sT);
    k_v2conv<<<H, 256, 0, stream>>>(W2, b2, v1p, t1, v2, t2col, W2b);
    k_gemm_mfma<<<dim3(D / GBN, H / GBM), 256, 0, stream>>>(W2b, W1sT, eps2);
    k_relu2<<<H, 256, 0, stream>>>(eps2, t2col, v2, v2p, a2, t2);
    k_eps3<<<D / 64, 256, 0, stream>>>(eps2, W3, a2, r3);
    k_final<<<O, 256, 0, stream>>>(W3, b3, v2p, a2, t2col, t2, r3, out);
}

// Round 3
// 277.365 us; speedup vs baseline: 3.7075x; 1.7339x over previous
//
#include <hip/hip_runtime.h>
#include <math.h>

#define ZEPS  0.01f
#define ZMEAN 0.1307f
#define ZSIGMA 0.3081f

constexpr int D = 1024, H = 4096, O = 10;

using short8 = __attribute__((ext_vector_type(8))) short;
using f32x4  = __attribute__((ext_vector_type(4))) float;

__device__ inline unsigned short f2bf(float x) {  // RNE fp32 -> bf16 bits
    unsigned int u = __float_as_uint(x);
    u += 0x7FFFu + ((u >> 16) & 1u);
    return (unsigned short)(u >> 16);
}

// async 16B/lane global->LDS (lds dest = base + lane*16, wave-uniform base)
__device__ inline void gl_lds16(const void* g, void* l) {
    __builtin_amdgcn_global_load_lds(
        (const __attribute__((address_space(1))) unsigned int*)g,
        (__attribute__((address_space(3))) unsigned int*)l, 16, 0, 0);
}

// ---------------------------------------------------------------------------
__device__ inline void relu_params(float v, float r, float& vout, float& aout, float& tout) {
    float u = v + r, l = v - r;
    float denom = u - l;
    float slope = u / (denom == 0.f ? 1.f : denom);
    float term = (1.f - slope) * u * 0.5f;
    bool dead = (u <= 0.f);
    bool crossing = (u > 0.f) && (l < 0.f);
    vout = dead ? 0.f : (crossing ? (slope * v + term) : v);
    aout = dead ? 0.f : (crossing ? slope : 1.f);
    tout = (!dead && crossing) ? term : 0.f;
}

// ---------------------------------------------------------------------------
__global__ void k_setup(const float* __restrict__ x, float* __restrict__ values,
                        float* __restrict__ dcol, float* __restrict__ r3) {
    int j = blockIdx.x * blockDim.x + threadIdx.x;
    if (j < D) {
        float v = x[j];
        float up = fminf(v + ZEPS, 1.f);
        float lo = fmaxf(v - ZEPS, 0.f);
        values[j] = (up + lo - ZMEAN) / ZSIGMA;
        dcol[j]   = up / ZSIGMA;
    }
    if (blockIdx.x == 0 && threadIdx.x < 16) r3[threadIdx.x] = 0.f;
}

// v1 = W1@values+b1 ; r1 = |W1| @ d ; ReLU-1 params
__global__ __launch_bounds__(256) void k_layer1(const float* __restrict__ W1, const float* __restrict__ b1,
                                                const float* __restrict__ values, const float* __restrict__ dcol,
                                                float* __restrict__ v1p, float* __restrict__ a1,
                                                float* __restrict__ t1) {
    int i = blockIdx.x, tid = threadIdx.x;
    const float* row = W1 + (size_t)i * D;
    float sv = 0.f, sr = 0.f;
    for (int j = tid; j < D; j += 256) {
        float w = row[j];
        sv += w * values[j];
        sr += fabsf(w) * dcol[j];
    }
    __shared__ float red1[256], red2[256];
    red1[tid] = sv; red2[tid] = sr;
    __syncthreads();
    for (int off = 128; off; off >>= 1) {
        if (tid < off) { red1[tid] += red1[tid + off]; red2[tid] += red2[tid + off]; }
        __syncthreads();
    }
    if (tid == 0) {
        float v = red1[0] + b1[i];
        relu_params(v, red2[0], v1p[i], a1[i], t1[i]);
    }
}

// W1sT[j][k] = bf16( a1[k] * W1[k][j] * d[j] )  — transposed, k-contiguous
__global__ __launch_bounds__(256) void k_scaleT(const float* __restrict__ W1, const float* __restrict__ a1,
                                                const float* __restrict__ dcol,
                                                unsigned short* __restrict__ W1sT) {
    __shared__ float tile[32][33];
    int j0 = blockIdx.x * 32, k0 = blockIdx.y * 32;
    int r = threadIdx.x >> 3;         // 0..31
    int c = (threadIdx.x & 7) * 4;    // 0,4,..,28
    float4 w = *(const float4*)&W1[(size_t)(k0 + r) * D + j0 + c];
    float a = a1[k0 + r];
    tile[r][c + 0] = a * w.x * dcol[j0 + c + 0];
    tile[r][c + 1] = a * w.y * dcol[j0 + c + 1];
    tile[r][c + 2] = a * w.z * dcol[j0 + c + 2];
    tile[r][c + 3] = a * w.w * dcol[j0 + c + 3];
    __syncthreads();
    ushort4 o;
    o.x = f2bf(tile[c + 0][r]);
    o.y = f2bf(tile[c + 1][r]);
    o.z = f2bf(tile[c + 2][r]);
    o.w = f2bf(tile[c + 3][r]);
    *(ushort4*)&W1sT[(size_t)(j0 + r) * H + k0 + c] = o;
}

// v2 = W2@v1p + b2 ; t2col = W2@t1 ; fused W2 -> bf16 conversion
__global__ __launch_bounds__(256) void k_v2conv(const float* __restrict__ W2, const float* __restrict__ b2,
                                                const float* __restrict__ v1p, const float* __restrict__ t1,
                                                float* __restrict__ v2, float* __restrict__ t2col,
                                                unsigned short* __restrict__ W2b) {
    int i = blockIdx.x, tid = threadIdx.x;
    const float* row = W2 + (size_t)i * H;
    unsigned short* orow = W2b + (size_t)i * H;
    float sv = 0.f, st = 0.f;
    for (int k0 = tid * 4; k0 < H; k0 += 1024) {
        float4 w = *(const float4*)&row[k0];
        sv += w.x * v1p[k0] + w.y * v1p[k0 + 1] + w.z * v1p[k0 + 2] + w.w * v1p[k0 + 3];
        st += w.x * t1[k0] + w.y * t1[k0 + 1] + w.z * t1[k0 + 2] + w.w * t1[k0 + 3];
        ushort4 o;
        o.x = f2bf(w.x); o.y = f2bf(w.y); o.z = f2bf(w.z); o.w = f2bf(w.w);
        *(ushort4*)&orow[k0] = o;
    }
    __shared__ float red1[256], red2[256];
    red1[tid] = sv; red2[tid] = st;
    __syncthreads();
    for (int off = 128; off; off >>= 1) {
        if (tid < off) { red1[tid] += red1[tid + off]; red2[tid] += red2[tid + off]; }
        __syncthreads();
    }
    if (tid == 0) { v2[i] = red1[0] + b2[i]; t2col[i] = red2[0]; }
}

// ---------------------------------------------------------------------------
// eps2 = W2b @ W1sT^T : A=[M=4096][K=4096] bf16, B=[N=1024][K] bf16 (NT GEMM).
#define GBM 128
#define GBN 128
#define GBK 32
__global__ __launch_bounds__(256) void k_gemm_mfma(const unsigned short* __restrict__ A,
                                                   const unsigned short* __restrict__ B,
                                                   float* __restrict__ C) {
    const int N = D, K = H;
    __shared__ __align__(16) unsigned short As[GBM * GBK];
    __shared__ __align__(16) unsigned short Bs[GBN * GBK];
    int tid = threadIdx.x;
    int wave = tid >> 6, lane = tid & 63;
    int bm = blockIdx.y * GBM, bn = blockIdx.x * GBN;
    int wm = (wave >> 1) * 64, wn = (wave & 1) * 64;

    int sr = lane >> 2;                 // row within 16-row group
    int sc = lane & 3;                  // dest chunk 0..3
    int scp = sc ^ ((sr >> 1) & 3);     // permuted source chunk
    int rowA0 = wave * 32;

    int r15 = lane & 15, quad = lane >> 4;
    int ksw = (r15 >> 1) & 3;           // read-side swizzle key

    f32x4 acc[4][4];
#pragma unroll
    for (int p = 0; p < 4; ++p)
#pragma unroll
        for (int q = 0; q < 4; ++q) acc[p][q] = (f32x4){0.f, 0.f, 0.f, 0.f};

    for (int k0 = 0; k0 < K; k0 += GBK) {
#pragma unroll
        for (int g = 0; g < 2; ++g) {
            int ra = rowA0 + g * 16;
            gl_lds16(&A[(size_t)(bm + ra + sr) * K + k0 + scp * 8], &As[ra * GBK]);
            gl_lds16(&B[(size_t)(bn + ra + sr) * K + k0 + scp * 8], &Bs[ra * GBK]);
        }
        __syncthreads();

        short8 af[4], bf[4];
#pragma unroll
        for (int mt = 0; mt < 4; ++mt) {
            int rA = wm + mt * 16 + r15;
            af[mt] = *(const short8*)&As[rA * GBK + (quad ^ ksw) * 8];
        }
#pragma unroll
        for (int nt = 0; nt < 4; ++nt) {
            int rB = wn + nt * 16 + r15;
            bf[nt] = *(const short8*)&Bs[rB * GBK + (quad ^ ksw) * 8];
        }
#pragma unroll
        for (int mt = 0; mt < 4; ++mt)
#pragma unroll
            for (int nt = 0; nt < 4; ++nt)
                acc[mt][nt] = __builtin_amdgcn_mfma_f32_16x16x32_bf16(af[mt], bf[nt], acc[mt][nt], 0, 0, 0);
        __syncthreads();
    }

#pragma unroll
    for (int mt = 0; mt < 4; ++mt) {
        int gr = bm + wm + mt * 16 + quad * 4;
#pragma unroll
        for (int nt = 0; nt < 4; ++nt) {
            int gc = bn + wn + nt * 16 + r15;
            C[(size_t)(gr + 0) * N + gc] = acc[mt][nt][0];
            C[(size_t)(gr + 1) * N + gc] = acc[mt][nt][1];
            C[(size_t)(gr + 2) * N + gc] = acc[mt][nt][2];
            C[(size_t)(gr + 3) * N + gc] = acc[mt][nt][3];
        }
    }
}

// r2 = rowsum|eps2| + |t2col| ; ReLU-2 params
__global__ __launch_bounds__(256) void k_relu2(const float* __restrict__ eps2, const float* __restrict__ t2col,
                                               const float* __restrict__ v2, float* __restrict__ v2p,
                                               float* __restrict__ a2, float* __restrict__ t2) {
    int i = blockIdx.x, tid = threadIdx.x;
    const float* row = eps2 + (size_t)i * D;
    float s = 0.f;
    for (int j = tid; j < D; j += 256) s += fabsf(row[j]);
    __shared__ float red[256];
    red[tid] = s;
    __syncthreads();
    for (int off = 128; off; off >>= 1) {
        if (tid < off) red[tid] += red[tid + off];
        __syncthreads();
    }
    if (tid == 0) {
        float r = red[0] + fabsf(t2col[i]);
        relu_params(v2[i], r, v2p[i], a2[i], t2[i]);
    }
}

// w3s[i][o] = W3[o][i] * a2[i]  (o-contiguous so eps3a can scalar-load per i)
__global__ void k_w3s(const float* __restrict__ W3, const float* __restrict__ a2,
                      float* __restrict__ w3s) {
    int i = blockIdx.x * blockDim.x + threadIdx.x;
    if (i < H) {
        float a = a2[i];
#pragma unroll
        for (int o = 0; o < O; ++o) w3s[(size_t)i * O + o] = W3[(size_t)o * H + i] * a;
    }
}

// pbuf[ib][o][j] = sum over 128-row i-slice of w3s[i][o] * eps2[i][j]
__global__ __launch_bounds__(256) void k_eps3a(const float* __restrict__ eps2,
                                               const float* __restrict__ w3s,
                                               float* __restrict__ pbuf) {
    int jb = blockIdx.x, ib = blockIdx.y;
    int c = threadIdx.x & 63, s = threadIdx.x >> 6;
    int j = jb * 64 + c;
    int i0 = ib * 128 + s * 32;
    float acc[O];
#pragma unroll
    for (int o = 0; o < O; ++o) acc[o] = 0.f;
    for (int ii = 0; ii < 32; ++ii) {
        int i = i0 + ii;
        float e = eps2[(size_t)i * D + j];
        const float* w = &w3s[(size_t)i * O];
#pragma unroll
        for (int o = 0; o < O; ++o) acc[o] += w[o] * e;
    }
    __shared__ float sm[4][64][O];
#pragma unroll
    for (int o = 0; o < O; ++o) sm[s][c][o] = acc[o];
    __syncthreads();
    for (int idx = threadIdx.x; idx < 64 * O; idx += 256) {
        int o = idx >> 6, cc = idx & 63;
        float t = sm[0][cc][o] + sm[1][cc][o] + sm[2][cc][o] + sm[3][cc][o];
        pbuf[((size_t)ib * O + o) * D + jb * 64 + cc] = t;
    }
}

// r3[o] = sum_j | sum_ib pbuf[ib][o][j] |
__global__ __launch_bounds__(256) void k_eps3b(const float* __restrict__ pbuf, float* __restrict__ r3) {
    int o = blockIdx.x, tid = threadIdx.x;
    float s = 0.f;
    for (int j = tid; j < D; j += 256) {
        float t = 0.f;
#pragma unroll
        for (int ib = 0; ib < 32; ++ib) t += pbuf[((size_t)ib * O + o) * D + j];
        s += fabsf(t);
    }
    __shared__ float red[256];
    red[tid] = s;
    __syncthreads();
    for (int off = 128; off; off >>= 1) {
        if (tid < off) red[tid] += red[tid + off];
        __syncthreads();
    }
    if (tid == 0) r3[o] = red[0];
}

// v3 = W3@v2p + b3 ; c1 = W3@(a2*t2col) ; c2 = W3@t2 ; out = v3 +- (r3+|c1|+|c2|)
__global__ __launch_bounds__(256) void k_final(const float* __restrict__ W3, const float* __restrict__ b3,
                                               const float* __restrict__ v2p, const float* __restrict__ a2,
                                               const float* __restrict__ t2col, const float* __restrict__ t2,
                                               const float* __restrict__ r3, float* __restrict__ out) {
    int o = blockIdx.x, tid = threadIdx.x;
    const float* row = W3 + (size_t)o * H;
    float sv = 0.f, s1 = 0.f, s2 = 0.f;
    for (int i = tid; i < H; i += 256) {
        float w = row[i];
        sv += w * v2p[i];
        s1 += w * a2[i] * t2col[i];
        s2 += w * t2[i];
    }
    __shared__ float ra[256], rb[256], rc[256];
    ra[tid] = sv; rb[tid] = s1; rc[tid] = s2;
    __syncthreads();
    for (int off = 128; off; off >>= 1) {
        if (tid < off) { ra[tid] += ra[tid + off]; rb[tid] += rb[tid + off]; rc[tid] += rc[tid + off]; }
        __syncthreads();
    }
    if (tid == 0) {
        float v3 = ra[0] + b3[o];
        float rr = r3[o] + fabsf(rb[0]) + fabsf(rc[0]);
        out[o] = v3 + rr;       // u
        out[O + o] = v3 - rr;   // l
    }
}

// ---------------------------------------------------------------------------
extern "C" void kernel_launch(void* const* d_in, const int* in_sizes, int n_in,
                              void* d_out, int out_size, void* d_ws, size_t ws_size,
                              hipStream_t stream) {
    const float* x  = (const float*)d_in[0];
    const float* W1 = (const float*)d_in[1];
    const float* b1 = (const float*)d_in[2];
    const float* W2 = (const float*)d_in[3];
    const float* b2 = (const float*)d_in[4];
    const float* W3 = (const float*)d_in[5];
    const float* b3 = (const float*)d_in[6];
    float* out = (float*)d_out;

    float* p = (float*)d_ws;
    float* values = p; p += D;
    float* dcol   = p; p += D;
    float* v1p    = p; p += H;
    float* a1     = p; p += H;
    float* t1     = p; p += H;
    float* v2     = p; p += H;
    float* t2col  = p; p += H;
    float* v2p    = p; p += H;
    float* a2     = p; p += H;
    float* t2     = p; p += H;
    float* r3     = p; p += 16;
    p += 16;  // 16B alignment pad
    float* w3s    = p; p += H * O + 8;
    float* pbuf   = p; p += 32 * O * D;                       // 1.25 MB
    float* eps2   = p; p += (size_t)H * D;                    // 16 MB fp32
    unsigned short* W2b  = (unsigned short*)p;                // 32 MB bf16
    unsigned short* W1sT = W2b + (size_t)H * H;               // 8 MB bf16

    k_setup<<<dim3((D + 255) / 256), 256, 0, stream>>>(x, values, dcol, r3);
    k_layer1<<<H, 256, 0, stream>>>(W1, b1, values, dcol, v1p, a1, t1);
    k_scaleT<<<dim3(D / 32, H / 32), 256, 0, stream>>>(W1, a1, dcol, W1sT);
    k_v2conv<<<H, 256, 0, stream>>>(W2, b2, v1p, t1, v2, t2col, W2b);
    k_gemm_mfma<<<dim3(D / GBN, H / GBM), 256, 0, stream>>>(W2b, W1sT, eps2);
    k_relu2<<<H, 256, 0, stream>>>(eps2, t2col, v2, v2p, a2, t2);
    k_w3s<<<(H + 255) / 256, 256, 0, stream>>>(W3, a2, w3s);
    k_eps3a<<<dim3(D / 64, 32), 256, 0, stream>>>(eps2, w3s, pbuf);
    k_eps3b<<<O, 256, 0, stream>>>(pbuf, r3);
    k_final<<<O, 256, 0, stream>>>(W3, b3, v2p, a2, t2col, t2, r3, out);
}

// Round 4
// 228.329 us; speedup vs baseline: 4.5037x; 1.2148x over previous
//
#include <hip/hip_runtime.h>
#include <math.h>

#define ZEPS  0.01f
#define ZMEAN 0.1307f
#define ZSIGMA 0.3081f

constexpr int D = 1024, H = 4096, O = 10;

using short8 = __attribute__((ext_vector_type(8))) short;
using f32x4  = __attribute__((ext_vector_type(4))) float;

__device__ inline unsigned short f2bf(float x) {  // RNE fp32 -> bf16 bits
    unsigned int u = __float_as_uint(x);
    u += 0x7FFFu + ((u >> 16) & 1u);
    return (unsigned short)(u >> 16);
}

// async 16B/lane global->LDS (lds dest = base + lane*16, wave-uniform base)
__device__ inline void gl_lds16(const void* g, void* l) {
    __builtin_amdgcn_global_load_lds(
        (const __attribute__((address_space(1))) unsigned int*)g,
        (__attribute__((address_space(3))) unsigned int*)l, 16, 0, 0);
}

// ---------------------------------------------------------------------------
__device__ inline void relu_params(float v, float r, float& vout, float& aout, float& tout) {
    float u = v + r, l = v - r;
    float denom = u - l;
    float slope = u / (denom == 0.f ? 1.f : denom);
    float term = (1.f - slope) * u * 0.5f;
    bool dead = (u <= 0.f);
    bool crossing = (u > 0.f) && (l < 0.f);
    vout = dead ? 0.f : (crossing ? (slope * v + term) : v);
    aout = dead ? 0.f : (crossing ? slope : 1.f);
    tout = (!dead && crossing) ? term : 0.f;
}

// ---------------------------------------------------------------------------
__global__ void k_setup(const float* __restrict__ x, float* __restrict__ values,
                        float* __restrict__ dcol, float* __restrict__ r3) {
    int j = blockIdx.x * blockDim.x + threadIdx.x;
    if (j < D) {
        float v = x[j];
        float up = fminf(v + ZEPS, 1.f);
        float lo = fmaxf(v - ZEPS, 0.f);
        values[j] = (up + lo - ZMEAN) / ZSIGMA;
        dcol[j]   = up / ZSIGMA;
    }
    if (blockIdx.x == 0 && threadIdx.x < 16) r3[threadIdx.x] = 0.f;
}

// v1 = W1@values+b1 ; r1 = |W1| @ d ; ReLU-1 params
__global__ __launch_bounds__(256) void k_layer1(const float* __restrict__ W1, const float* __restrict__ b1,
                                                const float* __restrict__ values, const float* __restrict__ dcol,
                                                float* __restrict__ v1p, float* __restrict__ a1,
                                                float* __restrict__ t1) {
    int i = blockIdx.x, tid = threadIdx.x;
    const float* row = W1 + (size_t)i * D;
    float sv = 0.f, sr = 0.f;
    for (int j = tid; j < D; j += 256) {
        float w = row[j];
        sv += w * values[j];
        sr += fabsf(w) * dcol[j];
    }
    __shared__ float red1[256], red2[256];
    red1[tid] = sv; red2[tid] = sr;
    __syncthreads();
    for (int off = 128; off; off >>= 1) {
        if (tid < off) { red1[tid] += red1[tid + off]; red2[tid] += red2[tid + off]; }
        __syncthreads();
    }
    if (tid == 0) {
        float v = red1[0] + b1[i];
        relu_params(v, red2[0], v1p[i], a1[i], t1[i]);
    }
}

// W1sT[j][k] = bf16( a1[k] * W1[k][j] * d[j] )  — transposed, k-contiguous
__global__ __launch_bounds__(256) void k_scaleT(const float* __restrict__ W1, const float* __restrict__ a1,
                                                const float* __restrict__ dcol,
                                                unsigned short* __restrict__ W1sT) {
    __shared__ float tile[32][33];
    int j0 = blockIdx.x * 32, k0 = blockIdx.y * 32;
    int r = threadIdx.x >> 3;         // 0..31
    int c = (threadIdx.x & 7) * 4;    // 0,4,..,28
    float4 w = *(const float4*)&W1[(size_t)(k0 + r) * D + j0 + c];
    float a = a1[k0 + r];
    tile[r][c + 0] = a * w.x * dcol[j0 + c + 0];
    tile[r][c + 1] = a * w.y * dcol[j0 + c + 1];
    tile[r][c + 2] = a * w.z * dcol[j0 + c + 2];
    tile[r][c + 3] = a * w.w * dcol[j0 + c + 3];
    __syncthreads();
    ushort4 o;
    o.x = f2bf(tile[c + 0][r]);
    o.y = f2bf(tile[c + 1][r]);
    o.z = f2bf(tile[c + 2][r]);
    o.w = f2bf(tile[c + 3][r]);
    *(ushort4*)&W1sT[(size_t)(j0 + r) * H + k0 + c] = o;
}

// v2 = W2@v1p + b2 ; t2col = W2@t1 ; fused W2 -> bf16 conversion
__global__ __launch_bounds__(256) void k_v2conv(const float* __restrict__ W2, const float* __restrict__ b2,
                                                const float* __restrict__ v1p, const float* __restrict__ t1,
                                                float* __restrict__ v2, float* __restrict__ t2col,
                                                unsigned short* __restrict__ W2b) {
    int i = blockIdx.x, tid = threadIdx.x;
    const float* row = W2 + (size_t)i * H;
    unsigned short* orow = W2b + (size_t)i * H;
    float sv = 0.f, st = 0.f;
    for (int k0 = tid * 4; k0 < H; k0 += 1024) {
        float4 w = *(const float4*)&row[k0];
        sv += w.x * v1p[k0] + w.y * v1p[k0 + 1] + w.z * v1p[k0 + 2] + w.w * v1p[k0 + 3];
        st += w.x * t1[k0] + w.y * t1[k0 + 1] + w.z * t1[k0 + 2] + w.w * t1[k0 + 3];
        ushort4 o;
        o.x = f2bf(w.x); o.y = f2bf(w.y); o.z = f2bf(w.z); o.w = f2bf(w.w);
        *(ushort4*)&orow[k0] = o;
    }
    __shared__ float red1[256], red2[256];
    red1[tid] = sv; red2[tid] = st;
    __syncthreads();
    for (int off = 128; off; off >>= 1) {
        if (tid < off) { red1[tid] += red1[tid + off]; red2[tid] += red2[tid + off]; }
        __syncthreads();
    }
    if (tid == 0) { v2[i] = red1[0] + b2[i]; t2col[i] = red2[0]; }
}

// ---------------------------------------------------------------------------
// eps2 = W2b @ W1sT^T, split-K=2: grid (8, 32, 2), each block 128x128 x K/2.
// BK=64 (32 KB LDS), XOR chunk-swizzle c^(row&7) -> uniform 8-acc/bank b128 reads.
#define GBK 64
__global__ __launch_bounds__(256) void k_gemm_mfma(const unsigned short* __restrict__ A,
                                                   const unsigned short* __restrict__ B,
                                                   float* __restrict__ C) {
    const int N = D, K = H;
    __shared__ __align__(16) unsigned short As[128 * GBK];
    __shared__ __align__(16) unsigned short Bs[128 * GBK];
    int tid = threadIdx.x;
    int wave = tid >> 6, lane = tid & 63;
    int bm = blockIdx.y * 128, bn = blockIdx.x * 128;
    int kbeg = blockIdx.z * (K / 2), kend = kbeg + K / 2;
    float* Cz = C + (size_t)blockIdx.z * ((size_t)H * D);
    int wm = (wave >> 1) * 64, wn = (wave & 1) * 64;

    int sr = lane >> 3;            // row within 8-row staging group
    int sc = lane & 7;             // dest chunk 0..7
    int scp = sc ^ sr;             // permuted source chunk
    int r15 = lane & 15, quad = lane >> 4, key = r15 & 7;

    f32x4 acc[4][4];
#pragma unroll
    for (int p = 0; p < 4; ++p)
#pragma unroll
        for (int q = 0; q < 4; ++q) acc[p][q] = (f32x4){0.f, 0.f, 0.f, 0.f};

    for (int k0 = kbeg; k0 < kend; k0 += GBK) {
#pragma unroll
        for (int g = 0; g < 4; ++g) {
            int row = wave * 32 + g * 8;
            gl_lds16(&A[(size_t)(bm + row + sr) * K + k0 + scp * 8], &As[row * GBK]);
            gl_lds16(&B[(size_t)(bn + row + sr) * K + k0 + scp * 8], &Bs[row * GBK]);
        }
        __syncthreads();
#pragma unroll
        for (int kk = 0; kk < 2; ++kk) {
            short8 af[4], bf[4];
#pragma unroll
            for (int mt = 0; mt < 4; ++mt)
                af[mt] = *(const short8*)&As[(wm + mt * 16 + r15) * GBK + (((kk * 4 + quad) ^ key)) * 8];
#pragma unroll
            for (int nt = 0; nt < 4; ++nt)
                bf[nt] = *(const short8*)&Bs[(wn + nt * 16 + r15) * GBK + (((kk * 4 + quad) ^ key)) * 8];
#pragma unroll
            for (int mt = 0; mt < 4; ++mt)
#pragma unroll
                for (int nt = 0; nt < 4; ++nt)
                    acc[mt][nt] = __builtin_amdgcn_mfma_f32_16x16x32_bf16(af[mt], bf[nt], acc[mt][nt], 0, 0, 0);
        }
        __syncthreads();
    }

    // epilogue: C row = quad*4+reg, col = lane&15
#pragma unroll
    for (int mt = 0; mt < 4; ++mt) {
        int gr = bm + wm + mt * 16 + quad * 4;
#pragma unroll
        for (int nt = 0; nt < 4; ++nt) {
            int gc = bn + wn + nt * 16 + r15;
            Cz[(size_t)(gr + 0) * N + gc] = acc[mt][nt][0];
            Cz[(size_t)(gr + 1) * N + gc] = acc[mt][nt][1];
            Cz[(size_t)(gr + 2) * N + gc] = acc[mt][nt][2];
            Cz[(size_t)(gr + 3) * N + gc] = acc[mt][nt][3];
        }
    }
}

// r2 = rowsum|e1+e2| + |t2col| ; ReLU-2 params
__global__ __launch_bounds__(256) void k_relu2(const float* __restrict__ e1, const float* __restrict__ e2,
                                               const float* __restrict__ t2col,
                                               const float* __restrict__ v2, float* __restrict__ v2p,
                                               float* __restrict__ a2, float* __restrict__ t2) {
    int i = blockIdx.x, tid = threadIdx.x;
    float4 a = ((const float4*)(e1 + (size_t)i * D))[tid];
    float4 b = ((const float4*)(e2 + (size_t)i * D))[tid];
    float s = fabsf(a.x + b.x) + fabsf(a.y + b.y) + fabsf(a.z + b.z) + fabsf(a.w + b.w);
    __shared__ float red[256];
    red[tid] = s;
    __syncthreads();
    for (int off = 128; off; off >>= 1) {
        if (tid < off) red[tid] += red[tid + off];
        __syncthreads();
    }
    if (tid == 0) {
        float r = red[0] + fabsf(t2col[i]);
        relu_params(v2[i], r, v2p[i], a2[i], t2[i]);
    }
}

// w3s[i][o] = W3[o][i] * a2[i]
__global__ void k_w3s(const float* __restrict__ W3, const float* __restrict__ a2,
                      float* __restrict__ w3s) {
    int i = blockIdx.x * blockDim.x + threadIdx.x;
    if (i < H) {
        float a = a2[i];
#pragma unroll
        for (int o = 0; o < O; ++o) w3s[(size_t)i * O + o] = W3[(size_t)o * H + i] * a;
    }
}

// pbuf[ib][o][j] = sum over 128-row i-slice of w3s[i][o] * (e1+e2)[i][j]
__global__ __launch_bounds__(256) void k_eps3a(const float* __restrict__ e1, const float* __restrict__ e2,
                                               const float* __restrict__ w3s,
                                               float* __restrict__ pbuf) {
    int jb = blockIdx.x, ib = blockIdx.y;
    int c = threadIdx.x & 63, s = threadIdx.x >> 6;
    int j = jb * 64 + c;
    int i0 = ib * 128 + s * 32;
    float acc[O];
#pragma unroll
    for (int o = 0; o < O; ++o) acc[o] = 0.f;
    for (int ii = 0; ii < 32; ++ii) {
        int i = i0 + ii;
        float e = e1[(size_t)i * D + j] + e2[(size_t)i * D + j];
        const float* w = &w3s[(size_t)i * O];
#pragma unroll
        for (int o = 0; o < O; ++o) acc[o] += w[o] * e;
    }
    __shared__ float sm[4][64][O];
#pragma unroll
    for (int o = 0; o < O; ++o) sm[s][c][o] = acc[o];
    __syncthreads();
    for (int idx = threadIdx.x; idx < 64 * O; idx += 256) {
        int o = idx >> 6, cc = idx & 63;
        float t = sm[0][cc][o] + sm[1][cc][o] + sm[2][cc][o] + sm[3][cc][o];
        pbuf[((size_t)ib * O + o) * D + jb * 64 + cc] = t;
    }
}

// r3[o] = sum_j | sum_ib pbuf[ib][o][j] |
__global__ __launch_bounds__(256) void k_eps3b(const float* __restrict__ pbuf, float* __restrict__ r3) {
    int o = blockIdx.x, tid = threadIdx.x;
    float s = 0.f;
    for (int j = tid; j < D; j += 256) {
        float t = 0.f;
#pragma unroll
        for (int ib = 0; ib < 32; ++ib) t += pbuf[((size_t)ib * O + o) * D + j];
        s += fabsf(t);
    }
    __shared__ float red[256];
    red[tid] = s;
    __syncthreads();
    for (int off = 128; off; off >>= 1) {
        if (tid < off) red[tid] += red[tid + off];
        __syncthreads();
    }
    if (tid == 0) r3[o] = red[0];
}

// v3 = W3@v2p + b3 ; c1 = W3@(a2*t2col) ; c2 = W3@t2 ; out = v3 +- (r3+|c1|+|c2|)
__global__ __launch_bounds__(256) void k_final(const float* __restrict__ W3, const float* __restrict__ b3,
                                               const float* __restrict__ v2p, const float* __restrict__ a2,
                                               const float* __restrict__ t2col, const float* __restrict__ t2,
                                               const float* __restrict__ r3, float* __restrict__ out) {
    int o = blockIdx.x, tid = threadIdx.x;
    const float* row = W3 + (size_t)o * H;
    float sv = 0.f, s1 = 0.f, s2 = 0.f;
    for (int i = tid; i < H; i += 256) {
        float w = row[i];
        sv += w * v2p[i];
        s1 += w * a2[i] * t2col[i];
        s2 += w * t2[i];
    }
    __shared__ float ra[256], rb[256], rc[256];
    ra[tid] = sv; rb[tid] = s1; rc[tid] = s2;
    __syncthreads();
    for (int off = 128; off; off >>= 1) {
        if (tid < off) { ra[tid] += ra[tid + off]; rb[tid] += rb[tid + off]; rc[tid] += rc[tid + off]; }
        __syncthreads();
    }
    if (tid == 0) {
        float v3 = ra[0] + b3[o];
        float rr = r3[o] + fabsf(rb[0]) + fabsf(rc[0]);
        out[o] = v3 + rr;       // u
        out[O + o] = v3 - rr;   // l
    }
}

// ---------------------------------------------------------------------------
extern "C" void kernel_launch(void* const* d_in, const int* in_sizes, int n_in,
                              void* d_out, int out_size, void* d_ws, size_t ws_size,
                              hipStream_t stream) {
    const float* x  = (const float*)d_in[0];
    const float* W1 = (const float*)d_in[1];
    const float* b1 = (const float*)d_in[2];
    const float* W2 = (const float*)d_in[3];
    const float* b2 = (const float*)d_in[4];
    const float* W3 = (const float*)d_in[5];
    const float* b3 = (const float*)d_in[6];
    float* out = (float*)d_out;

    float* p = (float*)d_ws;
    float* values = p; p += D;
    float* dcol   = p; p += D;
    float* v1p    = p; p += H;
    float* a1     = p; p += H;
    float* t1     = p; p += H;
    float* v2     = p; p += H;
    float* t2col  = p; p += H;
    float* v2p    = p; p += H;
    float* a2     = p; p += H;
    float* t2     = p; p += H;
    float* r3     = p; p += 16;
    p += 16;  // 16B alignment pad
    float* w3s    = p; p += H * O + 8;
    float* pbuf   = p; p += 32 * O * D;                       // 1.25 MB
    float* eps2   = p; p += (size_t)2 * H * D;                // 2 x 16 MB fp32 (split-K partials)
    unsigned short* W2b  = (unsigned short*)p;                // 32 MB bf16
    unsigned short* W1sT = W2b + (size_t)H * H;               // 8 MB bf16
    float* eps2b = eps2 + (size_t)H * D;

    k_setup<<<dim3((D + 255) / 256), 256, 0, stream>>>(x, values, dcol, r3);
    k_layer1<<<H, 256, 0, stream>>>(W1, b1, values, dcol, v1p, a1, t1);
    k_scaleT<<<dim3(D / 32, H / 32), 256, 0, stream>>>(W1, a1, dcol, W1sT);
    k_v2conv<<<H, 256, 0, stream>>>(W2, b2, v1p, t1, v2, t2col, W2b);
    k_gemm_mfma<<<dim3(D / 128, H / 128, 2), 256, 0, stream>>>(W2b, W1sT, eps2);
    k_relu2<<<H, 256, 0, stream>>>(eps2, eps2b, t2col, v2, v2p, a2, t2);
    k_w3s<<<(H + 255) / 256, 256, 0, stream>>>(W3, a2, w3s);
    k_eps3a<<<dim3(D / 64, 32), 256, 0, stream>>>(eps2, eps2b, w3s, pbuf);
    k_eps3b<<<O, 256, 0, stream>>>(pbuf, r3);
    k_final<<<O, 256, 0, stream>>>(W3, b3, v2p, a2, t2col, t2, r3, out);
}

// Round 5
// 221.635 us; speedup vs baseline: 4.6397x; 1.0302x over previous
//
#include <hip/hip_runtime.h>
#include <math.h>

#define ZEPS  0.01f
#define ZMEAN 0.1307f
#define ZSIGMA 0.3081f

constexpr int D = 1024, H = 4096, O = 10;

using short8 = __attribute__((ext_vector_type(8))) short;
using f32x4  = __attribute__((ext_vector_type(4))) float;

__device__ inline unsigned short f2bf(float x) {  // RNE fp32 -> bf16 bits
    unsigned int u = __float_as_uint(x);
    u += 0x7FFFu + ((u >> 16) & 1u);
    return (unsigned short)(u >> 16);
}

// async 16B/lane global->LDS (lds dest = base + lane*16, wave-uniform base)
__device__ inline void gl_lds16(const void* g, void* l) {
    __builtin_amdgcn_global_load_lds(
        (const __attribute__((address_space(1))) unsigned int*)g,
        (__attribute__((address_space(3))) unsigned int*)l, 16, 0, 0);
}

__device__ inline float zval(float xv) {  // normalized center
    float up = fminf(xv + ZEPS, 1.f);
    float lo = fmaxf(xv - ZEPS, 0.f);
    return (up + lo - ZMEAN) / ZSIGMA;
}
__device__ inline float zdia(float xv) {  // eps diagonal
    return fminf(xv + ZEPS, 1.f) / ZSIGMA;
}

// ---------------------------------------------------------------------------
__device__ inline void relu_params(float v, float r, float& vout, float& aout, float& tout) {
    float u = v + r, l = v - r;
    float denom = u - l;
    float slope = u / (denom == 0.f ? 1.f : denom);
    float term = (1.f - slope) * u * 0.5f;
    bool dead = (u <= 0.f);
    bool crossing = (u > 0.f) && (l < 0.f);
    vout = dead ? 0.f : (crossing ? (slope * v + term) : v);
    aout = dead ? 0.f : (crossing ? slope : 1.f);
    tout = (!dead && crossing) ? term : 0.f;
}

// ---------------------------------------------------------------------------
// v1 = W1@values+b1 ; r1 = |W1| @ d ; ReLU-1 params (normalize computed inline)
__global__ __launch_bounds__(256) void k_layer1(const float* __restrict__ W1, const float* __restrict__ b1,
                                                const float* __restrict__ x,
                                                float* __restrict__ v1p, float* __restrict__ a1,
                                                float* __restrict__ t1) {
    int i = blockIdx.x, tid = threadIdx.x;
    const float* row = W1 + (size_t)i * D;
    float sv = 0.f, sr = 0.f;
    for (int j = tid; j < D; j += 256) {
        float w = row[j];
        float xv = x[j];
        sv += w * zval(xv);
        sr += fabsf(w) * zdia(xv);
    }
    __shared__ float red1[256], red2[256];
    red1[tid] = sv; red2[tid] = sr;
    __syncthreads();
    for (int off = 128; off; off >>= 1) {
        if (tid < off) { red1[tid] += red1[tid + off]; red2[tid] += red2[tid + off]; }
        __syncthreads();
    }
    if (tid == 0) {
        float v = red1[0] + b1[i];
        relu_params(v, red2[0], v1p[i], a1[i], t1[i]);
    }
}

// W1sT[j][k] = bf16( a1[k] * W1[k][j] * d[j] )  — transposed, k-contiguous
__global__ __launch_bounds__(256) void k_scaleT(const float* __restrict__ W1, const float* __restrict__ a1,
                                                const float* __restrict__ x,
                                                unsigned short* __restrict__ W1sT) {
    __shared__ float tile[32][33];
    int j0 = blockIdx.x * 32, k0 = blockIdx.y * 32;
    int r = threadIdx.x >> 3;         // 0..31
    int c = (threadIdx.x & 7) * 4;    // 0,4,..,28
    float4 w = *(const float4*)&W1[(size_t)(k0 + r) * D + j0 + c];
    float4 xx = *(const float4*)&x[j0 + c];
    float a = a1[k0 + r];
    tile[r][c + 0] = a * w.x * zdia(xx.x);
    tile[r][c + 1] = a * w.y * zdia(xx.y);
    tile[r][c + 2] = a * w.z * zdia(xx.z);
    tile[r][c + 3] = a * w.w * zdia(xx.w);
    __syncthreads();
    ushort4 o;
    o.x = f2bf(tile[c + 0][r]);
    o.y = f2bf(tile[c + 1][r]);
    o.z = f2bf(tile[c + 2][r]);
    o.w = f2bf(tile[c + 3][r]);
    *(ushort4*)&W1sT[(size_t)(j0 + r) * H + k0 + c] = o;
}

// v2 = W2@v1p + b2 ; t2col = W2@t1 ; fused W2 -> bf16 conversion
__global__ __launch_bounds__(256) void k_v2conv(const float* __restrict__ W2, const float* __restrict__ b2,
                                                const float* __restrict__ v1p, const float* __restrict__ t1,
                                                float* __restrict__ v2, float* __restrict__ t2col,
                                                unsigned short* __restrict__ W2b) {
    int i = blockIdx.x, tid = threadIdx.x;
    const float* row = W2 + (size_t)i * H;
    unsigned short* orow = W2b + (size_t)i * H;
    float sv = 0.f, st = 0.f;
    for (int k0 = tid * 4; k0 < H; k0 += 1024) {
        float4 w = *(const float4*)&row[k0];
        sv += w.x * v1p[k0] + w.y * v1p[k0 + 1] + w.z * v1p[k0 + 2] + w.w * v1p[k0 + 3];
        st += w.x * t1[k0] + w.y * t1[k0 + 1] + w.z * t1[k0 + 2] + w.w * t1[k0 + 3];
        ushort4 o;
        o.x = f2bf(w.x); o.y = f2bf(w.y); o.z = f2bf(w.z); o.w = f2bf(w.w);
        *(ushort4*)&orow[k0] = o;
    }
    __shared__ float red1[256], red2[256];
    red1[tid] = sv; red2[tid] = st;
    __syncthreads();
    for (int off = 128; off; off >>= 1) {
        if (tid < off) { red1[tid] += red1[tid + off]; red2[tid] += red2[tid + off]; }
        __syncthreads();
    }
    if (tid == 0) { v2[i] = red1[0] + b2[i]; t2col[i] = red2[0]; }
}

// ---------------------------------------------------------------------------
// eps2 = W2b @ W1sT^T, split-K=2. 1-D grid of 512, XCD-aware remap:
// XCD u = b%8 owns z = u>>2 and y-tiles [(u&3)*8, (u&3)*8+8) x all 8 n-tiles
// -> per-XCD L2 working set ~8 MB instead of all of A.
// BK=64 (32 KB LDS), XOR chunk-swizzle c^(row&7) -> conflict-free b128 reads.
#define GBK 64
__global__ __launch_bounds__(256) void k_gemm_mfma(const unsigned short* __restrict__ A,
                                                   const unsigned short* __restrict__ B,
                                                   float* __restrict__ C) {
    const int N = D, K = H;
    __shared__ __align__(16) unsigned short As[128 * GBK];
    __shared__ __align__(16) unsigned short Bs[128 * GBK];
    int b = blockIdx.x;
    int u = b & 7, v = b >> 3;
    int z = u >> 2;
    int y = (u & 3) * 8 + (v >> 3);
    int xb = v & 7;
    int tid = threadIdx.x;
    int wave = tid >> 6, lane = tid & 63;
    int bm = y * 128, bn = xb * 128;
    int kbeg = z * (K / 2), kend = kbeg + K / 2;
    float* Cz = C + (size_t)z * ((size_t)H * D);
    int wm = (wave >> 1) * 64, wn = (wave & 1) * 64;

    int sr = lane >> 3;            // row within 8-row staging group
    int sc = lane & 7;             // dest chunk 0..7
    int scp = sc ^ sr;             // permuted source chunk
    int r15 = lane & 15, quad = lane >> 4, key = r15 & 7;

    f32x4 acc[4][4];
#pragma unroll
    for (int p = 0; p < 4; ++p)
#pragma unroll
        for (int q = 0; q < 4; ++q) acc[p][q] = (f32x4){0.f, 0.f, 0.f, 0.f};

    for (int k0 = kbeg; k0 < kend; k0 += GBK) {
#pragma unroll
        for (int g = 0; g < 4; ++g) {
            int row = wave * 32 + g * 8;
            gl_lds16(&A[(size_t)(bm + row + sr) * K + k0 + scp * 8], &As[row * GBK]);
            gl_lds16(&B[(size_t)(bn + row + sr) * K + k0 + scp * 8], &Bs[row * GBK]);
        }
        __syncthreads();
#pragma unroll
        for (int kk = 0; kk < 2; ++kk) {
            short8 af[4], bf[4];
#pragma unroll
            for (int mt = 0; mt < 4; ++mt)
                af[mt] = *(const short8*)&As[(wm + mt * 16 + r15) * GBK + (((kk * 4 + quad) ^ key)) * 8];
#pragma unroll
            for (int nt = 0; nt < 4; ++nt)
                bf[nt] = *(const short8*)&Bs[(wn + nt * 16 + r15) * GBK + (((kk * 4 + quad) ^ key)) * 8];
#pragma unroll
            for (int mt = 0; mt < 4; ++mt)
#pragma unroll
                for (int nt = 0; nt < 4; ++nt)
                    acc[mt][nt] = __builtin_amdgcn_mfma_f32_16x16x32_bf16(af[mt], bf[nt], acc[mt][nt], 0, 0, 0);
        }
        __syncthreads();
    }

    // epilogue: C row = quad*4+reg, col = lane&15
#pragma unroll
    for (int mt = 0; mt < 4; ++mt) {
        int gr = bm + wm + mt * 16 + quad * 4;
#pragma unroll
        for (int nt = 0; nt < 4; ++nt) {
            int gc = bn + wn + nt * 16 + r15;
            Cz[(size_t)(gr + 0) * N + gc] = acc[mt][nt][0];
            Cz[(size_t)(gr + 1) * N + gc] = acc[mt][nt][1];
            Cz[(size_t)(gr + 2) * N + gc] = acc[mt][nt][2];
            Cz[(size_t)(gr + 3) * N + gc] = acc[mt][nt][3];
        }
    }
}

// r2 = rowsum|e1+e2| + |t2col| ; ReLU-2 params ; fused w3s[i][o] = W3[o][i]*a2[i]
__global__ __launch_bounds__(256) void k_relu2(const float* __restrict__ e1, const float* __restrict__ e2,
                                               const float* __restrict__ t2col,
                                               const float* __restrict__ v2, const float* __restrict__ W3,
                                               float* __restrict__ v2p,
                                               float* __restrict__ a2, float* __restrict__ t2,
                                               float* __restrict__ w3s) {
    int i = blockIdx.x, tid = threadIdx.x;
    float4 a = ((const float4*)(e1 + (size_t)i * D))[tid];
    float4 b = ((const float4*)(e2 + (size_t)i * D))[tid];
    float s = fabsf(a.x + b.x) + fabsf(a.y + b.y) + fabsf(a.z + b.z) + fabsf(a.w + b.w);
    __shared__ float red[256];
    __shared__ float s_a2;
    red[tid] = s;
    __syncthreads();
    for (int off = 128; off; off >>= 1) {
        if (tid < off) red[tid] += red[tid + off];
        __syncthreads();
    }
    if (tid == 0) {
        float r = red[0] + fabsf(t2col[i]);
        float vo, ao, to;
        relu_params(v2[i], r, vo, ao, to);
        v2p[i] = vo; a2[i] = ao; t2[i] = to;
        s_a2 = ao;
    }
    __syncthreads();
    if (tid < O) w3s[(size_t)i * O + tid] = W3[(size_t)tid * H + i] * s_a2;
}

// pbuf[o][ib][j] = sum over 128-row i-slice ib of w3s[i][o] * (e1+e2)[i][j]
__global__ __launch_bounds__(256) void k_eps3a(const float* __restrict__ e1, const float* __restrict__ e2,
                                               const float* __restrict__ w3s,
                                               float* __restrict__ pbuf) {
    int jb = blockIdx.x, ib = blockIdx.y;      // 16 x 32
    int jj = threadIdx.x & 15, s = threadIdx.x >> 4;
    int j = jb * 64 + jj * 4;
    int i0 = ib * 128 + s * 8;
    float acc[4][O];
#pragma unroll
    for (int c = 0; c < 4; ++c)
#pragma unroll
        for (int o = 0; o < O; ++o) acc[c][o] = 0.f;
    for (int ii = 0; ii < 8; ++ii) {
        int i = i0 + ii;
        float4 a = *(const float4*)&e1[(size_t)i * D + j];
        float4 b = *(const float4*)&e2[(size_t)i * D + j];
        float e0 = a.x + b.x, ee1 = a.y + b.y, ee2 = a.z + b.z, ee3 = a.w + b.w;
        const float* w = &w3s[(size_t)i * O];
#pragma unroll
        for (int o = 0; o < O; ++o) {
            float wo = w[o];
            acc[0][o] += wo * e0; acc[1][o] += wo * ee1;
            acc[2][o] += wo * ee2; acc[3][o] += wo * ee3;
        }
    }
    __shared__ float sm[16][64][O];  // 40 KB
#pragma unroll
    for (int c = 0; c < 4; ++c)
#pragma unroll
        for (int o = 0; o < O; ++o) sm[s][jj * 4 + c][o] = acc[c][o];
    __syncthreads();
    for (int idx = threadIdx.x; idx < 64 * O; idx += 256) {
        int col = idx / O, o = idx % O;
        float t = 0.f;
#pragma unroll
        for (int ss = 0; ss < 16; ++ss) t += sm[ss][col][o];
        pbuf[((size_t)o * 32 + ib) * D + jb * 64 + col] = t;
    }
}

// fused eps3b + final: r3[o] = sum_j |sum_ib pbuf[o][ib][j]| ; dots ; output
__global__ __launch_bounds__(256) void k_final(const float* __restrict__ W3, const float* __restrict__ b3,
                                               const float* __restrict__ v2p, const float* __restrict__ a2,
                                               const float* __restrict__ t2col, const float* __restrict__ t2,
                                               const float* __restrict__ pbuf, float* __restrict__ out) {
    int o = blockIdx.x, tid = threadIdx.x;
    float s3 = 0.f;
    for (int j = tid; j < D; j += 256) {
        float t = 0.f;
#pragma unroll
        for (int ib = 0; ib < 32; ++ib) t += pbuf[((size_t)o * 32 + ib) * D + j];
        s3 += fabsf(t);
    }
    const float* row = W3 + (size_t)o * H;
    float sv = 0.f, s1 = 0.f, s2 = 0.f;
    for (int i = tid; i < H; i += 256) {
        float w = row[i];
        sv += w * v2p[i];
        s1 += w * a2[i] * t2col[i];
        s2 += w * t2[i];
    }
    __shared__ float ra[256], rb[256], rc[256], rd[256];
    ra[tid] = sv; rb[tid] = s1; rc[tid] = s2; rd[tid] = s3;
    __syncthreads();
    for (int off = 128; off; off >>= 1) {
        if (tid < off) {
            ra[tid] += ra[tid + off]; rb[tid] += rb[tid + off];
            rc[tid] += rc[tid + off]; rd[tid] += rd[tid + off];
        }
        __syncthreads();
    }
    if (tid == 0) {
        float v3 = ra[0] + b3[o];
        float rr = rd[0] + fabsf(rb[0]) + fabsf(rc[0]);
        out[o] = v3 + rr;       // u
        out[O + o] = v3 - rr;   // l
    }
}

// ---------------------------------------------------------------------------
extern "C" void kernel_launch(void* const* d_in, const int* in_sizes, int n_in,
                              void* d_out, int out_size, void* d_ws, size_t ws_size,
                              hipStream_t stream) {
    const float* x  = (const float*)d_in[0];
    const float* W1 = (const float*)d_in[1];
    const float* b1 = (const float*)d_in[2];
    const float* W2 = (const float*)d_in[3];
    const float* b2 = (const float*)d_in[4];
    const float* W3 = (const float*)d_in[5];
    const float* b3 = (const float*)d_in[6];
    float* out = (float*)d_out;

    float* p = (float*)d_ws;
    float* v1p    = p; p += H;
    float* a1     = p; p += H;
    float* t1     = p; p += H;
    float* v2     = p; p += H;
    float* t2col  = p; p += H;
    float* v2p    = p; p += H;
    float* a2     = p; p += H;
    float* t2     = p; p += H;
    float* w3s    = p; p += H * O + 8;
    float* pbuf   = p; p += 32 * O * D;                       // 1.25 MB
    float* eps2   = p; p += (size_t)2 * H * D;                // 2 x 16 MB fp32 (split-K partials)
    unsigned short* W2b  = (unsigned short*)p;                // 32 MB bf16
    unsigned short* W1sT = W2b + (size_t)H * H;               // 8 MB bf16
    float* eps2b = eps2 + (size_t)H * D;

    k_layer1<<<H, 256, 0, stream>>>(W1, b1, x, v1p, a1, t1);
    k_scaleT<<<dim3(D / 32, H / 32), 256, 0, stream>>>(W1, a1, x, W1sT);
    k_v2conv<<<H, 256, 0, stream>>>(W2, b2, v1p, t1, v2, t2col, W2b);
    k_gemm_mfma<<<512, 256, 0, stream>>>(W2b, W1sT, eps2);
    k_relu2<<<H, 256, 0, stream>>>(eps2, eps2b, t2col, v2, W3, v2p, a2, t2, w3s);
    k_eps3a<<<dim3(D / 64, 32), 256, 0, stream>>>(eps2, eps2b, w3s, pbuf);
    k_final<<<O, 256, 0, stream>>>(W3, b3, v2p, a2, t2col, t2, pbuf, out);
}